// Round 6
// baseline (349.524 us; speedup 1.0000x reference)
//
#include <hip/hip_runtime.h>

#define T_SEQ 128
#define NF 256
#define NH 30
#define NG 120           // 4*NH
#define NBATCH 1024
#define M_ROWS (NBATCH * T_SEQ)   // 131072

// ws byte offsets:
//   [0, 512)            bias0c[128] = b_ih0 + b_hh0, zero-padded
//   [512, 1024)         bias1c[128] = b_ih1 + b_hh1, zero-padded
//   [1024, 66560)       B0 hi frags: [8 ktiles][8 subtiles][64 lanes][8 bf16]
//   [66560, 132096)     B0 lo frags
//   [132096, 140288)    B1 hi frags: [1 ktile][8 subtiles][64 lanes][8 bf16]
//   [140288, 148480)    B1 lo frags
//   [148480, ...)       xg: [M_ROWS][120] fp32 (62.9 MB)
//                       - written as xg0 by gemm_xg
//                       - lstm0 overwrites cols 0..31 of each consumed row with
//                         packed bf16(hi|lo) h0 (in-place, zero extra ws)
//                       - gemm_xg1 reads the packed h0, overwrites all cols with xg1
//                       - lstm1 reads xg1
#define BIAS0_OFF 0
#define BIAS1_OFF 512
#define B0HI_OFF  1024
#define B0LO_OFF  (B0HI_OFF + 65536)
#define B1HI_OFF  (B0LO_OFF + 65536)   // 132096
#define B1LO_OFF  (B1HI_OFF + 8192)    // 140288
#define XG_OFF_B  (B1LO_OFF + 8192)    // 148480

typedef __attribute__((ext_vector_type(8))) short short8;
typedef __attribute__((ext_vector_type(4))) float float4v;
typedef __attribute__((ext_vector_type(2))) float v2f;

// ---------------------------------------------------------------- helpers
__device__ __forceinline__ short bf16_of(float f) {
  union { float f; unsigned u; } v; v.f = f;
  unsigned r = v.u + 0x7fffu + ((v.u >> 16) & 1u);  // RNE
  return (short)(r >> 16);
}
__device__ __forceinline__ float f_of_bf16(short s) {
  union { unsigned u; float f; } v; v.u = ((unsigned)(unsigned short)s) << 16;
  return v.f;
}

__device__ __forceinline__ float rl(float v, int j) {
  return __int_as_float(__builtin_amdgcn_readlane(__float_as_int(v), j));
}
__device__ __forceinline__ float fast_rcp(float x) { return __builtin_amdgcn_rcpf(x); }
__device__ __forceinline__ float act_mix(float x, float kIn, float kOut, float cOut) {
  float e = __expf(-kIn * x);
  float r = fast_rcp(1.0f + e);
  return fmaf(kOut, r, cOut);
}
__device__ __forceinline__ float tanh_fast(float x) {
  float e = __expf(-2.0f * x);
  float r = fast_rcp(1.0f + e);
  return fmaf(2.0f, r, -1.0f);
}
__device__ __forceinline__ v2f fma2(float s, v2f b, v2f c) {
  v2f a = {s, s};
  return __builtin_elementwise_fma(a, b, c);
}

// ---------------------------------------------------------------- prep
// blocks 0..15 : w_ih0 -> split bf16 hi/lo MFMA B-frags (8 ktiles) + bias0
// blocks 16..17: w_ih1 -> split bf16 hi/lo MFMA B-frags (1 ktile, K=32) + bias1
__global__ void prep_kernel(const float* __restrict__ w_ih0,
                            const float* __restrict__ b_ih0,
                            const float* __restrict__ b_hh0,
                            const float* __restrict__ w_ih1,
                            const float* __restrict__ b_ih1,
                            const float* __restrict__ b_hh1,
                            unsigned char* __restrict__ ws) {
  int gid = blockIdx.x * 256 + threadIdx.x;
  float* bias0 = (float*)(ws + BIAS0_OFF);
  float* bias1 = (float*)(ws + BIAS1_OFF);
  if (gid < 128) bias0[gid] = (gid < NG) ? (b_ih0[gid] + b_hh0[gid]) : 0.0f;

  if (gid < 4096) {
    int lane = gid & 63;
    int ts = gid >> 6;
    int t = ts >> 3, s = ts & 7;
    int n = s * 16 + (lane & 15);
    int k0 = t * 32 + (lane >> 4) * 8;
    short8 hi, lo;
#pragma unroll
    for (int j = 0; j < 8; ++j) {
      float v = (n < NG) ? w_ih0[n * NF + k0 + j] : 0.0f;
      short h = bf16_of(v);
      hi[j] = h;
      lo[j] = bf16_of(v - f_of_bf16(h));
    }
    *(short8*)(ws + B0HI_OFF + (size_t)gid * 16) = hi;
    *(short8*)(ws + B0LO_OFF + (size_t)gid * 16) = lo;
  } else {
    int q = gid - 4096;  // 0..511
    if (q < 128) bias1[q] = (q < NG) ? (b_ih1[q] + b_hh1[q]) : 0.0f;
    int lane = q & 63;
    int s = q >> 6;
    int n = s * 16 + (lane & 15);
    int k0 = (lane >> 4) * 8;
    short8 hi, lo;
#pragma unroll
    for (int j = 0; j < 8; ++j) {
      int k = k0 + j;
      float v = (n < NG && k < NH) ? w_ih1[n * NH + k] : 0.0f;
      short h = bf16_of(v);
      hi[j] = h;
      lo[j] = bf16_of(v - f_of_bf16(h));
    }
    *(short8*)(ws + B1HI_OFF + (size_t)q * 16) = hi;
    *(short8*)(ws + B1LO_OFF + (size_t)q * 16) = lo;
  }
}

// ---------------------------------------------------------------- GEMM0: xg0 = x @ w_ih0^T + bias0 (split-bf16 MFMA)
__global__ __launch_bounds__(256, 3) void gemm_xg(const float* __restrict__ x,
                                                  const unsigned char* __restrict__ ws,
                                                  float* __restrict__ xg) {
  __shared__ short lds_B[2][8 * 2 * 64 * 8];   // [buf][(s*2+plane)*64 + lane][8]
  const int tid = threadIdx.x;
  const int lane = tid & 63;
  const int wave = tid >> 6;
  const int r15 = lane & 15;
  const int quad = lane >> 4;
  const int rowbase = blockIdx.x * 128 + wave * 32;

  const short* __restrict__ Bhi = (const short*)(ws + B0HI_OFF);
  const short* __restrict__ Blo = (const short*)(ws + B0LO_OFF);
  const float* __restrict__ bias = (const float*)(ws + BIAS0_OFF);

  float4v acc[2][8];
#pragma unroll
  for (int s = 0; s < 8; ++s) {
    float b = bias[s * 16 + r15];
    float4v bv = {b, b, b, b};
    acc[0][s] = bv;
    acc[1][s] = bv;
  }

  const float* xptr[2];
  xptr[0] = x + (size_t)(rowbase + r15) * NF + quad * 8;
  xptr[1] = x + (size_t)(rowbase + 16 + r15) * NF + quad * 8;

#pragma unroll
  for (int i = 0; i < 2; ++i) {
    int s = wave * 2 + i;
    const short* ghi = Bhi + ((size_t)(0 * 8 + s) * 64 + lane) * 8;
    const short* glo = Blo + ((size_t)(0 * 8 + s) * 64 + lane) * 8;
    short* lhi = &lds_B[0][(s * 2 + 0) * 64 * 8];
    short* llo = &lds_B[0][(s * 2 + 1) * 64 * 8];
    __builtin_amdgcn_global_load_lds((const __attribute__((address_space(1))) void*)ghi,
                                     (__attribute__((address_space(3))) void*)lhi, 16, 0, 0);
    __builtin_amdgcn_global_load_lds((const __attribute__((address_space(1))) void*)glo,
                                     (__attribute__((address_space(3))) void*)llo, 16, 0, 0);
  }

  short8 ahi[2], alo[2];
#pragma unroll
  for (int g = 0; g < 2; ++g) {
    float4 p0 = *(const float4*)(xptr[g] + 0);
    float4 p1 = *(const float4*)(xptr[g] + 4);
    float f[8] = {p0.x, p0.y, p0.z, p0.w, p1.x, p1.y, p1.z, p1.w};
#pragma unroll
    for (int j = 0; j < 8; ++j) {
      short h = bf16_of(f[j]);
      ahi[g][j] = h;
      alo[g][j] = bf16_of(f[j] - f_of_bf16(h));
    }
  }
  __syncthreads();

  for (int t = 0; t < 8; ++t) {
    const int buf = t & 1;
    float4 anx[2][2];
    if (t < 7) {
#pragma unroll
      for (int i = 0; i < 2; ++i) {
        int s = wave * 2 + i;
        const short* ghi = Bhi + ((size_t)((t + 1) * 8 + s) * 64 + lane) * 8;
        const short* glo = Blo + ((size_t)((t + 1) * 8 + s) * 64 + lane) * 8;
        short* lhi = &lds_B[buf ^ 1][(s * 2 + 0) * 64 * 8];
        short* llo = &lds_B[buf ^ 1][(s * 2 + 1) * 64 * 8];
        __builtin_amdgcn_global_load_lds((const __attribute__((address_space(1))) void*)ghi,
                                         (__attribute__((address_space(3))) void*)lhi, 16, 0, 0);
        __builtin_amdgcn_global_load_lds((const __attribute__((address_space(1))) void*)glo,
                                         (__attribute__((address_space(3))) void*)llo, 16, 0, 0);
      }
#pragma unroll
      for (int g = 0; g < 2; ++g) {
        anx[g][0] = *(const float4*)(xptr[g] + (t + 1) * 32);
        anx[g][1] = *(const float4*)(xptr[g] + (t + 1) * 32 + 4);
      }
    }

#pragma unroll
    for (int s = 0; s < 8; ++s) {
      const short8 bh = *(const short8*)&lds_B[buf][((s * 2 + 0) * 64 + lane) * 8];
      const short8 bl = *(const short8*)&lds_B[buf][((s * 2 + 1) * 64 + lane) * 8];
#pragma unroll
      for (int g = 0; g < 2; ++g) {
        acc[g][s] = __builtin_amdgcn_mfma_f32_16x16x32_bf16(ahi[g], bh, acc[g][s], 0, 0, 0);
        acc[g][s] = __builtin_amdgcn_mfma_f32_16x16x32_bf16(ahi[g], bl, acc[g][s], 0, 0, 0);
        acc[g][s] = __builtin_amdgcn_mfma_f32_16x16x32_bf16(alo[g], bh, acc[g][s], 0, 0, 0);
      }
    }

    if (t < 7) {
#pragma unroll
      for (int g = 0; g < 2; ++g) {
        float f[8] = {anx[g][0].x, anx[g][0].y, anx[g][0].z, anx[g][0].w,
                      anx[g][1].x, anx[g][1].y, anx[g][1].z, anx[g][1].w};
#pragma unroll
        for (int j = 0; j < 8; ++j) {
          short h = bf16_of(f[j]);
          ahi[g][j] = h;
          alo[g][j] = bf16_of(f[j] - f_of_bf16(h));
        }
      }
    }
    __syncthreads();
  }

#pragma unroll
  for (int g = 0; g < 2; ++g) {
    const int row0 = rowbase + g * 16 + quad * 4;
#pragma unroll
    for (int s = 0; s < 8; ++s) {
      const int col = s * 16 + r15;
      if (col < NG) {
#pragma unroll
        for (int i = 0; i < 4; ++i) {
          xg[(size_t)(row0 + i) * NG + col] = acc[g][s][i];
        }
      }
    }
  }
}

// ---------------------------------------------------------------- lstm0: layer-0 recurrence
// One wave per batch element. ONLY w_hh0 weights (30 v2f = 60 VGPRs) -> fits
// the allocator's comfortable budget, no rematerialization (the R3-R5 killer).
// Writes h0 as packed bf16(hi|lo) u32 in-place into xg cols 0..31 of the
// just-consumed row (that row's gates are dead after this step).
__global__ __attribute__((amdgpu_waves_per_eu(1, 1))) void __launch_bounds__(64)
lstm0_kern(float* __restrict__ xg, const float* __restrict__ w_hh0) {
  const int b = blockIdx.x;
  const int lane = threadIdx.x;
  const bool hiHalf = lane >= 32;
  const int l = hiHalf ? (lane - 32) : lane;
  const int lc = (l < NH) ? l : (NH - 1);
  const int gA = hiHalf ? (60 + lc) : lc;   // lo: i-row; hi: g-row
  const int gB = gA + NH;                   // lo: f-row; hi: o-row

  const float kInA = hiHalf ? 2.0f : 1.0f;
  const float kOutA = hiHalf ? 2.0f : 1.0f;
  const float cOutA = hiHalf ? -1.0f : 0.0f;

  v2f wAB0[NH];
#pragma unroll
  for (int j = 0; j < NH; ++j) {
    wAB0[j] = (v2f){w_hh0[gA * NH + j], w_hh0[gB * NH + j]};
  }

  float* __restrict__ xgb = xg + (size_t)b * T_SEQ * NG;
  float c0 = 0.0f, h0 = 0.0f;
  float xA = xgb[gA], xB = xgb[gB];

#pragma unroll 1
  for (int t = 0; t < T_SEQ; ++t) {
    const int tn = (t + 1 < T_SEQ) ? (t + 1) : (T_SEQ - 1);
    float xnA = xgb[(size_t)tn * NG + gA];
    float xnB = xgb[(size_t)tn * NG + gB];

    v2f s = {xA, xB}, s2 = {0.0f, 0.0f};
#pragma unroll
    for (int j = 0; j < NH; j += 2) {
      float hj = rl(h0, j);
      float hj1 = rl(h0, j + 1);
      s = fma2(hj, wAB0[j], s);
      s2 = fma2(hj1, wAB0[j + 1], s2);
    }
    s += s2;

    float aA = act_mix(s.x, kInA, kOutA, cOutA);
    float aB = act_mix(s.y, 1.0f, 1.0f, 0.0f);
    float gg = __shfl_down(aA, 32);
    float oo = __shfl_down(aB, 32);
    c0 = fmaf(aB, c0, aA * gg);
    h0 = oo * tanh_fast(c0);

    // pack h0 -> bf16 hi|lo u32; store into cols 0..31 of the consumed row
    short hh = bf16_of(h0);
    unsigned hi = (unsigned short)hh;
    unsigned lo = (unsigned short)bf16_of(h0 - f_of_bf16(hh));
    unsigned pk = (hi << 16) | lo;
    if (lane < 32) {
      ((unsigned*)(xgb + (size_t)t * NG))[lane] = (lane < NH) ? pk : 0u;
    }

    xA = xnA;
    xB = xnB;
  }
}

// ---------------------------------------------------------------- GEMM1: xg1 = h0 @ w_ih1^T + bias1 (K=32, pre-split A)
// Reads packed bf16(hi|lo) h0 from xg cols 0..31, overwrites all cols with xg1.
// Per-block rows are disjoint; within a block all A reads precede the epilogue.
__global__ __launch_bounds__(256) void gemm_xg1(float* __restrict__ xg,
                                                const unsigned char* __restrict__ ws) {
  __shared__ short lds_B[8 * 2 * 64 * 8];   // 16 KB: [(s*2+plane)*64 + lane][8]
  const int tid = threadIdx.x;
  const int lane = tid & 63;
  const int wave = tid >> 6;
  const int r15 = lane & 15;
  const int quad = lane >> 4;
  const int rowbase = blockIdx.x * 128 + wave * 32;

  const short* __restrict__ Bhi = (const short*)(ws + B1HI_OFF);
  const short* __restrict__ Blo = (const short*)(ws + B1LO_OFF);
  const float* __restrict__ bias = (const float*)(ws + BIAS1_OFF);

#pragma unroll
  for (int i = 0; i < 2; ++i) {
    int s = wave * 2 + i;
    const short* ghi = Bhi + ((size_t)s * 64 + lane) * 8;
    const short* glo = Blo + ((size_t)s * 64 + lane) * 8;
    short* lhi = &lds_B[(s * 2 + 0) * 64 * 8];
    short* llo = &lds_B[(s * 2 + 1) * 64 * 8];
    __builtin_amdgcn_global_load_lds((const __attribute__((address_space(1))) void*)ghi,
                                     (__attribute__((address_space(3))) void*)lhi, 16, 0, 0);
    __builtin_amdgcn_global_load_lds((const __attribute__((address_space(1))) void*)glo,
                                     (__attribute__((address_space(3))) void*)llo, 16, 0, 0);
  }

  float4v acc[2][8];
#pragma unroll
  for (int s = 0; s < 8; ++s) {
    float b = bias[s * 16 + r15];
    float4v bv = {b, b, b, b};
    acc[0][s] = bv;
    acc[1][s] = bv;
  }

  // A: packed h0 u32 at cols quad*8 .. quad*8+7 of rows rowbase+r15 (+16)
  short8 ahi[2], alo[2];
#pragma unroll
  for (int g = 0; g < 2; ++g) {
    const unsigned* ap =
        (const unsigned*)(xg + (size_t)(rowbase + g * 16 + r15) * NG) + quad * 8;
    uint4 q0 = *(const uint4*)(ap);
    uint4 q1 = *(const uint4*)(ap + 4);
    unsigned u[8] = {q0.x, q0.y, q0.z, q0.w, q1.x, q1.y, q1.z, q1.w};
#pragma unroll
    for (int j = 0; j < 8; ++j) {
      ahi[g][j] = (short)(u[j] >> 16);
      alo[g][j] = (short)(u[j] & 0xffffu);
    }
  }
  __syncthreads();

#pragma unroll
  for (int s = 0; s < 8; ++s) {
    const short8 bh = *(const short8*)&lds_B[((s * 2 + 0) * 64 + lane) * 8];
    const short8 bl = *(const short8*)&lds_B[((s * 2 + 1) * 64 + lane) * 8];
#pragma unroll
    for (int g = 0; g < 2; ++g) {
      acc[g][s] = __builtin_amdgcn_mfma_f32_16x16x32_bf16(ahi[g], bh, acc[g][s], 0, 0, 0);
      acc[g][s] = __builtin_amdgcn_mfma_f32_16x16x32_bf16(ahi[g], bl, acc[g][s], 0, 0, 0);
      acc[g][s] = __builtin_amdgcn_mfma_f32_16x16x32_bf16(alo[g], bh, acc[g][s], 0, 0, 0);
    }
  }

#pragma unroll
  for (int g = 0; g < 2; ++g) {
    const int row0 = rowbase + g * 16 + quad * 4;
#pragma unroll
    for (int s = 0; s < 8; ++s) {
      const int col = s * 16 + r15;
      if (col < NG) {
#pragma unroll
        for (int i = 0; i < 4; ++i) {
          xg[(size_t)(row0 + i) * NG + col] = acc[g][s][i];
        }
      }
    }
  }
}

// ---------------------------------------------------------------- lstm1: layer-1 recurrence + final linear
// ONLY w_hh1 weights (60 VGPRs). xg1 already contains input contribution+bias.
__global__ __attribute__((amdgpu_waves_per_eu(1, 1))) void __launch_bounds__(64)
lstm1_kern(const float* __restrict__ xg, const float* __restrict__ w_hh1,
           const float* __restrict__ w_lin, const float* __restrict__ b_lin,
           float* __restrict__ out) {
  const int b = blockIdx.x;
  const int lane = threadIdx.x;
  const bool hiHalf = lane >= 32;
  const int l = hiHalf ? (lane - 32) : lane;
  const int lc = (l < NH) ? l : (NH - 1);
  const int gA = hiHalf ? (60 + lc) : lc;
  const int gB = gA + NH;

  const float kInA = hiHalf ? 2.0f : 1.0f;
  const float kOutA = hiHalf ? 2.0f : 1.0f;
  const float cOutA = hiHalf ? -1.0f : 0.0f;

  v2f uAB1[NH];
#pragma unroll
  for (int j = 0; j < NH; ++j) {
    uAB1[j] = (v2f){w_hh1[gA * NH + j], w_hh1[gB * NH + j]};
  }

  const float* __restrict__ xgb = xg + (size_t)b * T_SEQ * NG;
  float c1 = 0.0f, h1 = 0.0f, acc = 0.0f;
  float xA = xgb[gA], xB = xgb[gB];
  float wl = w_lin[lc];

#pragma unroll 1
  for (int t = 0; t < T_SEQ; ++t) {
    const int tn = (t + 1 < T_SEQ) ? (t + 1) : (T_SEQ - 1);
    float xnA = xgb[(size_t)tn * NG + gA];
    float xnB = xgb[(size_t)tn * NG + gB];
    float wln = w_lin[tn * NH + lc];

    v2f s = {xA, xB}, s2 = {0.0f, 0.0f};
#pragma unroll
    for (int j = 0; j < NH; j += 2) {
      float hj = rl(h1, j);
      float hj1 = rl(h1, j + 1);
      s = fma2(hj, uAB1[j], s);
      s2 = fma2(hj1, uAB1[j + 1], s2);
    }
    s += s2;

    float aA = act_mix(s.x, kInA, kOutA, cOutA);
    float aB = act_mix(s.y, 1.0f, 1.0f, 0.0f);
    float gg = __shfl_down(aA, 32);
    float oo = __shfl_down(aB, 32);
    c1 = fmaf(aB, c1, aA * gg);
    h1 = oo * tanh_fast(c1);
    acc = fmaf(h1, wl, acc);

    xA = xnA;
    xB = xnB;
    wl = wln;
  }

  if (lane >= NH) acc = 0.0f;
#pragma unroll
  for (int off = 32; off > 0; off >>= 1) acc += __shfl_xor(acc, off);
  if (lane == 0) out[b] = acc + b_lin[0];
}

// ---------------------------------------------------------------- launch
extern "C" void kernel_launch(void* const* d_in, const int* in_sizes, int n_in,
                              void* d_out, int out_size, void* d_ws, size_t ws_size,
                              hipStream_t stream) {
  (void)in_sizes; (void)n_in; (void)out_size; (void)ws_size;
  const float* x     = (const float*)d_in[0];
  const float* w_ih0 = (const float*)d_in[1];
  const float* w_hh0 = (const float*)d_in[2];
  const float* b_ih0 = (const float*)d_in[3];
  const float* b_hh0 = (const float*)d_in[4];
  const float* w_ih1 = (const float*)d_in[5];
  const float* w_hh1 = (const float*)d_in[6];
  const float* b_ih1 = (const float*)d_in[7];
  const float* b_hh1 = (const float*)d_in[8];
  const float* w_lin = (const float*)d_in[9];
  const float* b_lin = (const float*)d_in[10];
  unsigned char* ws = (unsigned char*)d_ws;
  float* out = (float*)d_out;
  float* xg = (float*)(ws + XG_OFF_B);

  prep_kernel<<<18, 256, 0, stream>>>(w_ih0, b_ih0, b_hh0, w_ih1, b_ih1, b_hh1, ws);
  gemm_xg<<<M_ROWS / 128, 256, 0, stream>>>(x, ws, xg);
  lstm0_kern<<<NBATCH, 64, 0, stream>>>(xg, w_hh0);
  gemm_xg1<<<M_ROWS / 128, 256, 0, stream>>>(xg, ws);
  lstm1_kern<<<NBATCH, 64, 0, stream>>>(xg, w_hh1, w_lin, b_lin, out);
}

// Round 7
// 331.905 us; speedup vs baseline: 1.0531x; 1.0531x over previous
//
#include <hip/hip_runtime.h>

#define T_SEQ 128
#define NF 256
#define NH 30
#define NG 120           // 4*NH
#define NBATCH 1024
#define M_ROWS (NBATCH * T_SEQ)   // 131072

// ws byte offsets:
//   [0, 512)            bias0c[128] = b_ih0 + b_hh0, zero-padded
//   [512, 1024)         bias1c[128] = b_ih1 + b_hh1, zero-padded
//   [1024, 66560)       B0 hi frags: [8 ktiles][8 subtiles][64 lanes][8 bf16]
//   [66560, 132096)     B0 lo frags
//   [132096, 140288)    B1 hi frags: [1 ktile][8 subtiles][64 lanes][8 bf16]
//   [140288, 148480)    B1 lo frags
//   [148480, +62.9MB)   xg: [M_ROWS][120] fp32 (xg0, overwritten by xg1)
//   [+62.9MB, +79.7MB)  h0pk: [M_ROWS][32] u32 packed bf16(hi|lo) h0 (dense)
#define BIAS0_OFF 0
#define BIAS1_OFF 512
#define B0HI_OFF  1024
#define B0LO_OFF  (B0HI_OFF + 65536)
#define B1HI_OFF  (B0LO_OFF + 65536)   // 132096
#define B1LO_OFF  (B1HI_OFF + 8192)    // 140288
#define XG_OFF_B  (B1LO_OFF + 8192)    // 148480
#define H0PK_OFF  (XG_OFF_B + (size_t)M_ROWS * NG * 4)

typedef __attribute__((ext_vector_type(8))) short short8;
typedef __attribute__((ext_vector_type(4))) float float4v;
typedef __attribute__((ext_vector_type(2))) float v2f;

// ---------------------------------------------------------------- helpers
__device__ __forceinline__ short bf16_of(float f) {
  union { float f; unsigned u; } v; v.f = f;
  unsigned r = v.u + 0x7fffu + ((v.u >> 16) & 1u);  // RNE
  return (short)(r >> 16);
}
__device__ __forceinline__ float f_of_bf16(short s) {
  union { unsigned u; float f; } v; v.u = ((unsigned)(unsigned short)s) << 16;
  return v.f;
}

__device__ __forceinline__ float rl(float v, int j) {
  return __int_as_float(__builtin_amdgcn_readlane(__float_as_int(v), j));
}
__device__ __forceinline__ float fast_rcp(float x) { return __builtin_amdgcn_rcpf(x); }
__device__ __forceinline__ float act_mix(float x, float kIn, float kOut, float cOut) {
  float e = __expf(-kIn * x);
  float r = fast_rcp(1.0f + e);
  return fmaf(kOut, r, cOut);
}
__device__ __forceinline__ float tanh_fast(float x) {
  float e = __expf(-2.0f * x);
  float r = fast_rcp(1.0f + e);
  return fmaf(2.0f, r, -1.0f);
}
__device__ __forceinline__ v2f fma2(float s, v2f b, v2f c) {
  v2f a = {s, s};
  return __builtin_elementwise_fma(a, b, c);
}

// ---------------------------------------------------------------- prep
__global__ void prep_kernel(const float* __restrict__ w_ih0,
                            const float* __restrict__ b_ih0,
                            const float* __restrict__ b_hh0,
                            const float* __restrict__ w_ih1,
                            const float* __restrict__ b_ih1,
                            const float* __restrict__ b_hh1,
                            unsigned char* __restrict__ ws) {
  int gid = blockIdx.x * 256 + threadIdx.x;
  float* bias0 = (float*)(ws + BIAS0_OFF);
  float* bias1 = (float*)(ws + BIAS1_OFF);
  if (gid < 128) bias0[gid] = (gid < NG) ? (b_ih0[gid] + b_hh0[gid]) : 0.0f;

  if (gid < 4096) {
    int lane = gid & 63;
    int ts = gid >> 6;
    int t = ts >> 3, s = ts & 7;
    int n = s * 16 + (lane & 15);
    int k0 = t * 32 + (lane >> 4) * 8;
    short8 hi, lo;
#pragma unroll
    for (int j = 0; j < 8; ++j) {
      float v = (n < NG) ? w_ih0[n * NF + k0 + j] : 0.0f;
      short h = bf16_of(v);
      hi[j] = h;
      lo[j] = bf16_of(v - f_of_bf16(h));
    }
    *(short8*)(ws + B0HI_OFF + (size_t)gid * 16) = hi;
    *(short8*)(ws + B0LO_OFF + (size_t)gid * 16) = lo;
  } else {
    int q = gid - 4096;  // 0..511
    if (q < 128) bias1[q] = (q < NG) ? (b_ih1[q] + b_hh1[q]) : 0.0f;
    int lane = q & 63;
    int s = q >> 6;
    int n = s * 16 + (lane & 15);
    int k0 = (lane >> 4) * 8;
    short8 hi, lo;
#pragma unroll
    for (int j = 0; j < 8; ++j) {
      int k = k0 + j;
      float v = (n < NG && k < NH) ? w_ih1[n * NH + k] : 0.0f;
      short h = bf16_of(v);
      hi[j] = h;
      lo[j] = bf16_of(v - f_of_bf16(h));
    }
    *(short8*)(ws + B1HI_OFF + (size_t)q * 16) = hi;
    *(short8*)(ws + B1LO_OFF + (size_t)q * 16) = lo;
  }
}

// ---------------------------------------------------------------- GEMM0: xg0 = x @ w_ih0^T + bias0 (split-bf16 MFMA)
__global__ __launch_bounds__(256, 3) void gemm_xg(const float* __restrict__ x,
                                                  const unsigned char* __restrict__ ws,
                                                  float* __restrict__ xg) {
  __shared__ short lds_B[2][8 * 2 * 64 * 8];   // [buf][(s*2+plane)*64 + lane][8]
  const int tid = threadIdx.x;
  const int lane = tid & 63;
  const int wave = tid >> 6;
  const int r15 = lane & 15;
  const int quad = lane >> 4;
  const int rowbase = blockIdx.x * 128 + wave * 32;

  const short* __restrict__ Bhi = (const short*)(ws + B0HI_OFF);
  const short* __restrict__ Blo = (const short*)(ws + B0LO_OFF);
  const float* __restrict__ bias = (const float*)(ws + BIAS0_OFF);

  float4v acc[2][8];
#pragma unroll
  for (int s = 0; s < 8; ++s) {
    float b = bias[s * 16 + r15];
    float4v bv = {b, b, b, b};
    acc[0][s] = bv;
    acc[1][s] = bv;
  }

  const float* xptr[2];
  xptr[0] = x + (size_t)(rowbase + r15) * NF + quad * 8;
  xptr[1] = x + (size_t)(rowbase + 16 + r15) * NF + quad * 8;

#pragma unroll
  for (int i = 0; i < 2; ++i) {
    int s = wave * 2 + i;
    const short* ghi = Bhi + ((size_t)(0 * 8 + s) * 64 + lane) * 8;
    const short* glo = Blo + ((size_t)(0 * 8 + s) * 64 + lane) * 8;
    short* lhi = &lds_B[0][(s * 2 + 0) * 64 * 8];
    short* llo = &lds_B[0][(s * 2 + 1) * 64 * 8];
    __builtin_amdgcn_global_load_lds((const __attribute__((address_space(1))) void*)ghi,
                                     (__attribute__((address_space(3))) void*)lhi, 16, 0, 0);
    __builtin_amdgcn_global_load_lds((const __attribute__((address_space(1))) void*)glo,
                                     (__attribute__((address_space(3))) void*)llo, 16, 0, 0);
  }

  short8 ahi[2], alo[2];
#pragma unroll
  for (int g = 0; g < 2; ++g) {
    float4 p0 = *(const float4*)(xptr[g] + 0);
    float4 p1 = *(const float4*)(xptr[g] + 4);
    float f[8] = {p0.x, p0.y, p0.z, p0.w, p1.x, p1.y, p1.z, p1.w};
#pragma unroll
    for (int j = 0; j < 8; ++j) {
      short h = bf16_of(f[j]);
      ahi[g][j] = h;
      alo[g][j] = bf16_of(f[j] - f_of_bf16(h));
    }
  }
  __syncthreads();

  for (int t = 0; t < 8; ++t) {
    const int buf = t & 1;
    float4 anx[2][2];
    if (t < 7) {
#pragma unroll
      for (int i = 0; i < 2; ++i) {
        int s = wave * 2 + i;
        const short* ghi = Bhi + ((size_t)((t + 1) * 8 + s) * 64 + lane) * 8;
        const short* glo = Blo + ((size_t)((t + 1) * 8 + s) * 64 + lane) * 8;
        short* lhi = &lds_B[buf ^ 1][(s * 2 + 0) * 64 * 8];
        short* llo = &lds_B[buf ^ 1][(s * 2 + 1) * 64 * 8];
        __builtin_amdgcn_global_load_lds((const __attribute__((address_space(1))) void*)ghi,
                                         (__attribute__((address_space(3))) void*)lhi, 16, 0, 0);
        __builtin_amdgcn_global_load_lds((const __attribute__((address_space(1))) void*)glo,
                                         (__attribute__((address_space(3))) void*)llo, 16, 0, 0);
      }
#pragma unroll
      for (int g = 0; g < 2; ++g) {
        anx[g][0] = *(const float4*)(xptr[g] + (t + 1) * 32);
        anx[g][1] = *(const float4*)(xptr[g] + (t + 1) * 32 + 4);
      }
    }

#pragma unroll
    for (int s = 0; s < 8; ++s) {
      const short8 bh = *(const short8*)&lds_B[buf][((s * 2 + 0) * 64 + lane) * 8];
      const short8 bl = *(const short8*)&lds_B[buf][((s * 2 + 1) * 64 + lane) * 8];
#pragma unroll
      for (int g = 0; g < 2; ++g) {
        acc[g][s] = __builtin_amdgcn_mfma_f32_16x16x32_bf16(ahi[g], bh, acc[g][s], 0, 0, 0);
        acc[g][s] = __builtin_amdgcn_mfma_f32_16x16x32_bf16(ahi[g], bl, acc[g][s], 0, 0, 0);
        acc[g][s] = __builtin_amdgcn_mfma_f32_16x16x32_bf16(alo[g], bh, acc[g][s], 0, 0, 0);
      }
    }

    if (t < 7) {
#pragma unroll
      for (int g = 0; g < 2; ++g) {
        float f[8] = {anx[g][0].x, anx[g][0].y, anx[g][0].z, anx[g][0].w,
                      anx[g][1].x, anx[g][1].y, anx[g][1].z, anx[g][1].w};
#pragma unroll
        for (int j = 0; j < 8; ++j) {
          short h = bf16_of(f[j]);
          ahi[g][j] = h;
          alo[g][j] = bf16_of(f[j] - f_of_bf16(h));
        }
      }
    }
    __syncthreads();
  }

#pragma unroll
  for (int g = 0; g < 2; ++g) {
    const int row0 = rowbase + g * 16 + quad * 4;
#pragma unroll
    for (int s = 0; s < 8; ++s) {
      const int col = s * 16 + r15;
      if (col < NG) {
#pragma unroll
        for (int i = 0; i < 4; ++i) {
          xg[(size_t)(row0 + i) * NG + col] = acc[g][s][i];
        }
      }
    }
  }
}

// ---------------------------------------------------------------- lstm0: layer-0 recurrence
// One wave per batch element. ONLY w_hh0 (60 VGPRs, no remat). Depth-8
// prefetch ring (t-loop unrolled x8, static slots): xg loads issue 8 steps
// (~1200 cyc) before use -> covers HBM latency that killed R6 (1-step ring
// gave only ~150 cyc slack vs ~900 cyc latency). h0 packed bf16(hi|lo) ->
// dense h0pk[row][32] (coalesced 128B/row, no aliasing with xg reads).
__global__ __attribute__((amdgpu_waves_per_eu(1, 1))) void __launch_bounds__(64)
lstm0_kern(const float* __restrict__ xg, const float* __restrict__ w_hh0,
           unsigned* __restrict__ h0pk) {
  const int b = blockIdx.x;
  const int lane = threadIdx.x;
  const bool hiHalf = lane >= 32;
  const int l = hiHalf ? (lane - 32) : lane;
  const int lc = (l < NH) ? l : (NH - 1);
  const int gA = hiHalf ? (60 + lc) : lc;   // lo: i-row; hi: g-row
  const int gB = gA + NH;                   // lo: f-row; hi: o-row

  const float kInA = hiHalf ? 2.0f : 1.0f;
  const float kOutA = hiHalf ? 2.0f : 1.0f;
  const float cOutA = hiHalf ? -1.0f : 0.0f;

  v2f wAB0[NH];
#pragma unroll
  for (int j = 0; j < NH; ++j) {
    wAB0[j] = (v2f){w_hh0[gA * NH + j], w_hh0[gB * NH + j]};
  }

  const float* __restrict__ xgb = xg + (size_t)b * T_SEQ * NG;
  unsigned* __restrict__ pkb = h0pk + (size_t)b * T_SEQ * 32;
  float c0 = 0.0f, h0 = 0.0f;

  float xa[8], xb[8];
#pragma unroll
  for (int p = 0; p < 8; ++p) {
    xa[p] = xgb[(size_t)p * NG + gA];
    xb[p] = xgb[(size_t)p * NG + gB];
  }

#pragma unroll 1
  for (int tb = 0; tb < T_SEQ; tb += 8) {
#pragma unroll
    for (int u = 0; u < 8; ++u) {
      const int t = tb + u;
      const int tp = (t + 8 < T_SEQ) ? (t + 8) : (T_SEQ - 1);
      float xnA = xgb[(size_t)tp * NG + gA];   // 8 steps ahead
      float xnB = xgb[(size_t)tp * NG + gB];

      v2f s = {xa[u], xb[u]}, s2 = {0.0f, 0.0f};
#pragma unroll
      for (int j = 0; j < NH; j += 2) {
        float hj = rl(h0, j);
        float hj1 = rl(h0, j + 1);
        s = fma2(hj, wAB0[j], s);
        s2 = fma2(hj1, wAB0[j + 1], s2);
      }
      s += s2;

      float aA = act_mix(s.x, kInA, kOutA, cOutA);
      float aB = act_mix(s.y, 1.0f, 1.0f, 0.0f);
      float gg = __shfl_down(aA, 32);
      float oo = __shfl_down(aB, 32);
      c0 = fmaf(aB, c0, aA * gg);
      h0 = oo * tanh_fast(c0);

      short hh = bf16_of(h0);
      unsigned hi = (unsigned short)hh;
      unsigned lo = (unsigned short)bf16_of(h0 - f_of_bf16(hh));
      unsigned pk = (hi << 16) | lo;
      if (lane < 32) {
        pkb[(size_t)t * 32 + lane] = (lane < NH) ? pk : 0u;
      }

      xa[u] = xnA;
      xb[u] = xnB;
    }
  }
}

// ---------------------------------------------------------------- GEMM1: xg1 = h0 @ w_ih1^T + bias1 (K=32, pre-split A)
__global__ __launch_bounds__(256) void gemm_xg1(float* __restrict__ xg,
                                                const unsigned* __restrict__ h0pk,
                                                const unsigned char* __restrict__ ws) {
  __shared__ short lds_B[8 * 2 * 64 * 8];   // 16 KB
  const int tid = threadIdx.x;
  const int lane = tid & 63;
  const int wave = tid >> 6;
  const int r15 = lane & 15;
  const int quad = lane >> 4;
  const int rowbase = blockIdx.x * 128 + wave * 32;

  const short* __restrict__ Bhi = (const short*)(ws + B1HI_OFF);
  const short* __restrict__ Blo = (const short*)(ws + B1LO_OFF);
  const float* __restrict__ bias = (const float*)(ws + BIAS1_OFF);

#pragma unroll
  for (int i = 0; i < 2; ++i) {
    int s = wave * 2 + i;
    const short* ghi = Bhi + ((size_t)s * 64 + lane) * 8;
    const short* glo = Blo + ((size_t)s * 64 + lane) * 8;
    short* lhi = &lds_B[(s * 2 + 0) * 64 * 8];
    short* llo = &lds_B[(s * 2 + 1) * 64 * 8];
    __builtin_amdgcn_global_load_lds((const __attribute__((address_space(1))) void*)ghi,
                                     (__attribute__((address_space(3))) void*)lhi, 16, 0, 0);
    __builtin_amdgcn_global_load_lds((const __attribute__((address_space(1))) void*)glo,
                                     (__attribute__((address_space(3))) void*)llo, 16, 0, 0);
  }

  float4v acc[2][8];
#pragma unroll
  for (int s = 0; s < 8; ++s) {
    float b = bias[s * 16 + r15];
    float4v bv = {b, b, b, b};
    acc[0][s] = bv;
    acc[1][s] = bv;
  }

  // A: dense packed h0, row-major [row][32] u32
  short8 ahi[2], alo[2];
#pragma unroll
  for (int g = 0; g < 2; ++g) {
    const unsigned* ap = h0pk + (size_t)(rowbase + g * 16 + r15) * 32 + quad * 8;
    uint4 q0 = *(const uint4*)(ap);
    uint4 q1 = *(const uint4*)(ap + 4);
    unsigned u[8] = {q0.x, q0.y, q0.z, q0.w, q1.x, q1.y, q1.z, q1.w};
#pragma unroll
    for (int j = 0; j < 8; ++j) {
      ahi[g][j] = (short)(u[j] >> 16);
      alo[g][j] = (short)(u[j] & 0xffffu);
    }
  }
  __syncthreads();

#pragma unroll
  for (int s = 0; s < 8; ++s) {
    const short8 bh = *(const short8*)&lds_B[((s * 2 + 0) * 64 + lane) * 8];
    const short8 bl = *(const short8*)&lds_B[((s * 2 + 1) * 64 + lane) * 8];
#pragma unroll
    for (int g = 0; g < 2; ++g) {
      acc[g][s] = __builtin_amdgcn_mfma_f32_16x16x32_bf16(ahi[g], bh, acc[g][s], 0, 0, 0);
      acc[g][s] = __builtin_amdgcn_mfma_f32_16x16x32_bf16(ahi[g], bl, acc[g][s], 0, 0, 0);
      acc[g][s] = __builtin_amdgcn_mfma_f32_16x16x32_bf16(alo[g], bh, acc[g][s], 0, 0, 0);
    }
  }

#pragma unroll
  for (int g = 0; g < 2; ++g) {
    const int row0 = rowbase + g * 16 + quad * 4;
#pragma unroll
    for (int s = 0; s < 8; ++s) {
      const int col = s * 16 + r15;
      if (col < NG) {
#pragma unroll
        for (int i = 0; i < 4; ++i) {
          xg[(size_t)(row0 + i) * NG + col] = acc[g][s][i];
        }
      }
    }
  }
}

// ---------------------------------------------------------------- lstm1: layer-1 recurrence + final linear
__global__ __attribute__((amdgpu_waves_per_eu(1, 1))) void __launch_bounds__(64)
lstm1_kern(const float* __restrict__ xg, const float* __restrict__ w_hh1,
           const float* __restrict__ w_lin, const float* __restrict__ b_lin,
           float* __restrict__ out) {
  const int b = blockIdx.x;
  const int lane = threadIdx.x;
  const bool hiHalf = lane >= 32;
  const int l = hiHalf ? (lane - 32) : lane;
  const int lc = (l < NH) ? l : (NH - 1);
  const int gA = hiHalf ? (60 + lc) : lc;
  const int gB = gA + NH;

  const float kInA = hiHalf ? 2.0f : 1.0f;
  const float kOutA = hiHalf ? 2.0f : 1.0f;
  const float cOutA = hiHalf ? -1.0f : 0.0f;

  v2f uAB1[NH];
#pragma unroll
  for (int j = 0; j < NH; ++j) {
    uAB1[j] = (v2f){w_hh1[gA * NH + j], w_hh1[gB * NH + j]};
  }

  const float* __restrict__ xgb = xg + (size_t)b * T_SEQ * NG;
  float c1 = 0.0f, h1 = 0.0f, acc = 0.0f;

  float xa[8], xb[8], wlr[8];
#pragma unroll
  for (int p = 0; p < 8; ++p) {
    xa[p] = xgb[(size_t)p * NG + gA];
    xb[p] = xgb[(size_t)p * NG + gB];
    wlr[p] = w_lin[p * NH + lc];
  }

#pragma unroll 1
  for (int tb = 0; tb < T_SEQ; tb += 8) {
#pragma unroll
    for (int u = 0; u < 8; ++u) {
      const int t = tb + u;
      const int tp = (t + 8 < T_SEQ) ? (t + 8) : (T_SEQ - 1);
      float xnA = xgb[(size_t)tp * NG + gA];
      float xnB = xgb[(size_t)tp * NG + gB];
      float wln = w_lin[tp * NH + lc];

      v2f s = {xa[u], xb[u]}, s2 = {0.0f, 0.0f};
#pragma unroll
      for (int j = 0; j < NH; j += 2) {
        float hj = rl(h1, j);
        float hj1 = rl(h1, j + 1);
        s = fma2(hj, uAB1[j], s);
        s2 = fma2(hj1, uAB1[j + 1], s2);
      }
      s += s2;

      float aA = act_mix(s.x, kInA, kOutA, cOutA);
      float aB = act_mix(s.y, 1.0f, 1.0f, 0.0f);
      float gg = __shfl_down(aA, 32);
      float oo = __shfl_down(aB, 32);
      c1 = fmaf(aB, c1, aA * gg);
      h1 = oo * tanh_fast(c1);
      acc = fmaf(h1, wlr[u], acc);

      xa[u] = xnA;
      xb[u] = xnB;
      wlr[u] = wln;
    }
  }

  if (lane >= NH) acc = 0.0f;
#pragma unroll
  for (int off = 32; off > 0; off >>= 1) acc += __shfl_xor(acc, off);
  if (lane == 0) out[b] = acc + b_lin[0];
}

// ---------------------------------------------------------------- launch
extern "C" void kernel_launch(void* const* d_in, const int* in_sizes, int n_in,
                              void* d_out, int out_size, void* d_ws, size_t ws_size,
                              hipStream_t stream) {
  (void)in_sizes; (void)n_in; (void)out_size; (void)ws_size;
  const float* x     = (const float*)d_in[0];
  const float* w_ih0 = (const float*)d_in[1];
  const float* w_hh0 = (const float*)d_in[2];
  const float* b_ih0 = (const float*)d_in[3];
  const float* b_hh0 = (const float*)d_in[4];
  const float* w_ih1 = (const float*)d_in[5];
  const float* w_hh1 = (const float*)d_in[6];
  const float* b_ih1 = (const float*)d_in[7];
  const float* b_hh1 = (const float*)d_in[8];
  const float* w_lin = (const float*)d_in[9];
  const float* b_lin = (const float*)d_in[10];
  unsigned char* ws = (unsigned char*)d_ws;
  float* out = (float*)d_out;
  float* xg = (float*)(ws + XG_OFF_B);
  unsigned* h0pk = (unsigned*)(ws + H0PK_OFF);

  prep_kernel<<<18, 256, 0, stream>>>(w_ih0, b_ih0, b_hh0, w_ih1, b_ih1, b_hh1, ws);
  gemm_xg<<<M_ROWS / 128, 256, 0, stream>>>(x, ws, xg);
  lstm0_kern<<<NBATCH, 64, 0, stream>>>(xg, w_hh0, h0pk);
  gemm_xg1<<<M_ROWS / 128, 256, 0, stream>>>(xg, h0pk, ws);
  lstm1_kern<<<NBATCH, 64, 0, stream>>>(xg, w_hh1, w_lin, b_lin, out);
}